// Round 5
// baseline (107.024 us; speedup 1.0000x reference)
//
#include <hip/hip_runtime.h>
#include <stdint.h>

#define D_DIM 128
#define NROW 8192          // 2B
#define TEMP_INV 10.0f     // 1/0.1
#define L2EPS 1e-12f
#define LOG2E_X10 14.426950408889634f   // 10 / ln(2)

typedef __attribute__((ext_vector_type(8))) short short8;
typedef __attribute__((ext_vector_type(4))) float f32x4;

#define AS1 __attribute__((address_space(1)))
#define AS3 __attribute__((address_space(3)))

static __device__ inline void gload_lds16(const void* g, void* l) {
    __builtin_amdgcn_global_load_lds((const AS1 uint32_t*)g, (AS3 uint32_t*)l, 16, 0, 0);
}

static __device__ inline ushort f2bf(float f) {
    union { float f; uint32_t u; } v; v.f = f;
    uint32_t u = v.u;
    uint32_t r = (u + 0x7fffu + ((u >> 16) & 1u)) >> 16;   // RNE
    return (ushort)r;
}

// K1: L2-normalize rows of [x_i; x_j] -> bf16 Z; zero scalar accumulators.
__global__ __launch_bounds__(256) void k_normalize(
        const float* __restrict__ xi, const float* __restrict__ xj,
        ushort* __restrict__ z, float* __restrict__ pos_acc) {
    const int wave = threadIdx.x >> 6;
    const int lane = threadIdx.x & 63;
    const int row = blockIdx.x * 4 + wave;
    const float* src = (row < 4096) ? (xi + (size_t)row * D_DIM)
                                    : (xj + (size_t)(row - 4096) * D_DIM);
    float2 v = *(const float2*)(src + lane * 2);
    float ss = v.x * v.x + v.y * v.y;
#pragma unroll
    for (int m = 32; m >= 1; m >>= 1) ss += __shfl_xor(ss, m, 64);
    const float scale = 1.0f / fmaxf(sqrtf(ss), L2EPS);
    ushort2 o;
    o.x = f2bf(v.x * scale);
    o.y = f2bf(v.y * scale);
    *(ushort2*)(z + (size_t)row * D_DIM + lane * 2) = o;

    if (blockIdx.x == 0 && threadIdx.x == 0) pos_acc[0] = 0.0f;
}

// K2: block (rb=bid>>3, cc=bid&7) computes sim rows [rb*128,+128) x cols
// [cc*1024,+1024). A band staged once into 32 KB LDS (XOR swizzle), fragments
// hoisted to registers, then the SAME 32 KB is reused as the B double-buffer
// (2 x 16 KB) -> 32 KB/block total -> 5 blocks/CU resident (vs 2 at 64 KB).
// B streamed as 16 tiles of 64x128 via global_load_lds, prefetch overlapped
// with MFMA+exp. Row partials -> denom_part[cc][row], single writer.
__global__ __launch_bounds__(256, 4) void k_gemm(
        const ushort* __restrict__ z, float* __restrict__ denom_part,
        float* __restrict__ pos_acc) {
    __shared__ __align__(16) ushort lds[2][64 * 128];   // 32 KB total (aliased)
    ushort* flat = (ushort*)lds;

    const int bid = blockIdx.x;
    const int t = threadIdx.x;
    const int wave = t >> 6, lane = t & 63;
    const int quad = lane >> 4, lc = lane & 15;

    const int rb = bid >> 3;            // row band 0..63
    const int cc = bid & 7;             // col chunk 0..7
    const int rowbase = rb * 128;
    const int colbase = cc * 1024;

    // Stage A band (128 rows, contiguous 32 KB of Z); XOR swizzle:
    // 16B chunk g of row r lands at slot g ^ (r&15).
    {
        const ushort* za = z + (size_t)rowbase * D_DIM;
#pragma unroll
        for (int q = 0; q < 8; q++) {
            const int s = q * 256 + t;
            const int r = s >> 4;
            const int gc = (s & 15) ^ (r & 15);
            gload_lds16(za + (size_t)r * D_DIM + gc * 8, &flat[s * 8]);
        }
        asm volatile("s_waitcnt vmcnt(0)" ::: "memory");
        __syncthreads();
    }

    // Hoist A fragments: wave owns rows [wave*32, +32): 2 row-tiles x 4 K-chunks.
    short8 afr[2][4];
#pragma unroll
    for (int i = 0; i < 2; i++)
#pragma unroll
        for (int k = 0; k < 4; k++)
            afr[i][k] = *(const short8*)
                &flat[(wave * 32 + i * 16 + lc) * D_DIM + ((k * 4 + quad) ^ lc) * 8];
    __syncthreads();   // all A reads done before B0 DMA overwrites this LDS

    // First B tile into buffer 0.
    {
        const ushort* zb = z + (size_t)colbase * D_DIM;
#pragma unroll
        for (int q = 0; q < 4; q++) {
            const int s = q * 256 + t;
            const int r = s >> 4;
            const int gc = (s & 15) ^ (r & 15);
            gload_lds16(zb + (size_t)r * D_DIM + gc * 8, &lds[0][s * 8]);
        }
        asm volatile("s_waitcnt vmcnt(0)" ::: "memory");
        __syncthreads();
    }

    const bool diagblk = (cc == (rb >> 3));
    const bool posblk  = (cc == ((rb ^ 32) >> 3));
    const int diag_it2 = rb & 7;
    const int pos_it2  = (rb ^ 32) & 7;

    float rs[2][4] = {{0.f,0.f,0.f,0.f},{0.f,0.f,0.f,0.f}};
    float posp = 0.f;
    const int rgbase = rowbase + wave * 32 + quad * 4;   // + i*16 + r

    for (int it = 0; it < 16; it++) {
        const int cur = it & 1;
        if (it < 15) {  // prefetch next B tile into the other buffer
            const ushort* zb = z + (size_t)(colbase + (it + 1) * 64) * D_DIM;
#pragma unroll
            for (int q = 0; q < 4; q++) {
                const int s = q * 256 + t;
                const int r = s >> 4;
                const int gc = (s & 15) ^ (r & 15);
                gload_lds16(zb + (size_t)r * D_DIM + gc * 8, &lds[cur ^ 1][s * 8]);
            }
        }

        f32x4 acc[2][4];
#pragma unroll
        for (int i = 0; i < 2; i++)
#pragma unroll
            for (int j = 0; j < 4; j++) acc[i][j] = (f32x4){0.f, 0.f, 0.f, 0.f};

#pragma unroll
        for (int j = 0; j < 4; j++) {
            short8 bfr[4];
#pragma unroll
            for (int k = 0; k < 4; k++)
                bfr[k] = *(const short8*)
                    &lds[cur][(j * 16 + lc) * D_DIM + ((k * 4 + quad) ^ lc) * 8];
#pragma unroll
            for (int k = 0; k < 4; k++) {
                acc[0][j] = __builtin_amdgcn_mfma_f32_16x16x32_bf16(afr[0][k], bfr[k], acc[0][j], 0, 0, 0);
                acc[1][j] = __builtin_amdgcn_mfma_f32_16x16x32_bf16(afr[1][k], bfr[k], acc[1][j], 0, 0, 0);
            }
        }

        const bool dit = diagblk && ((it >> 1) == diag_it2);
        const bool pit = posblk && ((it >> 1) == pos_it2);
        if (dit || pit) {   // careful path: <= 2 of 16 iters, <= 1/8 of blocks
#pragma unroll
            for (int i = 0; i < 2; i++)
#pragma unroll
                for (int j = 0; j < 4; j++)
#pragma unroll
                    for (int r = 0; r < 4; r++) {
                        const float s = acc[i][j][r];
                        float e = exp2f(s * LOG2E_X10);
                        const int rg = rgbase + i * 16 + r;
                        const int cg = colbase + it * 64 + j * 16 + lc;
                        if (dit && rg == cg) e = 0.f;            // exclude diag
                        if (pit && cg == (rg ^ 4096)) posp += s; // positive
                        rs[i][r] += e;
                    }
        } else {            // hot path
#pragma unroll
            for (int i = 0; i < 2; i++)
#pragma unroll
                for (int j = 0; j < 4; j++)
#pragma unroll
                    for (int r = 0; r < 4; r++)
                        rs[i][r] += exp2f(acc[i][j][r] * LOG2E_X10);
        }

        asm volatile("s_waitcnt vmcnt(0)" ::: "memory");
        __syncthreads();
    }

    // Row partials: reduce over the 16 col-lanes, one store per row.
#pragma unroll
    for (int i = 0; i < 2; i++)
#pragma unroll
        for (int r = 0; r < 4; r++) {
            float v = rs[i][r];
            v += __shfl_xor(v, 1, 64);
            v += __shfl_xor(v, 2, 64);
            v += __shfl_xor(v, 4, 64);
            v += __shfl_xor(v, 8, 64);
            if (lc == 0)
                denom_part[(size_t)cc * NROW + rgbase + i * 16 + r] = v;
        }

    if (posblk) {
#pragma unroll
        for (int m = 32; m >= 1; m >>= 1) posp += __shfl_xor(posp, m, 64);
        if (lane == 0) atomicAdd(pos_acc, posp);
    }
}

// K3 (fused logsum+combine): one block, 1024 threads; each thread owns 8 rows.
__global__ __launch_bounds__(1024) void k_logsum(
        const float* __restrict__ denom_part, const float* __restrict__ pos_acc,
        float* __restrict__ out) {
    __shared__ float red[16];
    const int t = threadIdx.x;
    float v = 0.f;
#pragma unroll
    for (int rr = 0; rr < 8; rr++) {
        const int row = rr * 1024 + t;
        float d = 0.f;
#pragma unroll
        for (int p = 0; p < 8; p++) d += denom_part[(size_t)p * NROW + row];
        v += __logf(d);
    }
#pragma unroll
    for (int m = 32; m >= 1; m >>= 1) v += __shfl_xor(v, m, 64);
    if ((t & 63) == 0) red[t >> 6] = v;
    __syncthreads();
    if (t == 0) {
        float total = 0.f;
#pragma unroll
        for (int i = 0; i < 16; i++) total += red[i];
        out[0] = (total - pos_acc[0] * TEMP_INV) / (float)NROW;
    }
}

extern "C" void kernel_launch(void* const* d_in, const int* in_sizes, int n_in,
                              void* d_out, int out_size, void* d_ws, size_t ws_size,
                              hipStream_t stream) {
    const float* xi = (const float*)d_in[0];
    const float* xj = (const float*)d_in[1];
    ushort* z = (ushort*)d_ws;                                   // 2 MB bf16
    float* denom_part = (float*)((char*)d_ws + (size_t)NROW * D_DIM * sizeof(ushort)); // 8 x 8192 f32
    float* pos_acc = denom_part + 8 * NROW;
    float* out = (float*)d_out;

    hipLaunchKernelGGL(k_normalize, dim3(NROW / 4), dim3(256), 0, stream,
                       xi, xj, z, pos_acc);
    hipLaunchKernelGGL(k_gemm, dim3(512), dim3(256), 0, stream,
                       z, denom_part, pos_acc);
    hipLaunchKernelGGL(k_logsum, dim3(1), dim3(1024), 0, stream,
                       denom_part, pos_acc, out);
}